// Round 1
// baseline (536.279 us; speedup 1.0000x reference)
//
#include <hip/hip_runtime.h>
#include <math.h>

#define DH 512
#define CC 64
#define NB 2048
#define SCALE 0.044194173824159216f   // 1/sqrt(512)

// ---------------- wave helpers ----------------
__device__ __forceinline__ float wsum(float v) {
#pragma unroll
  for (int off = 32; off; off >>= 1) v += __shfl_xor(v, off, 64);
  return v;
}

// ============================================================================
// pre_kernel: blocks 0..255 compute wsA = W_q^T @ W_k (rows 0..1535) and
// wsM = W_v^T @ W_k (rows 1536..2047) with 64x64 tiles; block 256 does the
// bool-layout detection for `double` -> need[b] in {1,2}.
// ============================================================================
__global__ __launch_bounds__(128) void pre_kernel(const float* __restrict__ Wq,
                                                  const float* __restrict__ Wv,
                                                  const float* __restrict__ Wk,
                                                  float* __restrict__ Aout,
                                                  float* __restrict__ Mout,
                                                  const unsigned char* __restrict__ dbl,
                                                  int* __restrict__ need) {
  const int bx = blockIdx.x;
  const int t = threadIdx.x;
  if (bx == 256) {
    __shared__ int flagNZ, flagFP;
    if (t == 0) { flagNZ = 0; flagFP = 0; }
    __syncthreads();
    int nz = 0, fp = 0;
    for (int i = t; i < NB; i += 128) {
      if (i & 3) {
        unsigned char v = dbl[i];
        nz |= (v != 0);
        fp |= (v == 0x3f) | (v == 0x80);
      }
    }
    if (nz) atomicOr(&flagNZ, 1);
    if (fp) atomicOr(&flagFP, 1);
    __syncthreads();
    const int isFP = flagFP, isByte = flagNZ && !flagFP;
    for (int i = t; i < NB; i += 128) {
      int v;
      if (isFP)        v = (((const float*)dbl)[i] != 0.0f);
      else if (isByte) v = (dbl[i] != 0);
      else             v = (((const int*)dbl)[i] != 0);
      need[i] = v ? 2 : 1;
    }
    return;
  }
  __shared__ float As[16][64];
  __shared__ float Bs[16][64];
  const int mt = bx >> 3, nt = bx & 7;
  const int m0 = mt * 64, n0 = nt * 64;
  const bool isQ = (m0 < 1536);
  const float* Acol = isQ ? (Wq + m0) : (Wv + (m0 - 1536));
  const int lda = isQ ? 1536 : 512;
  float* Cout = isQ ? (Aout + (size_t)m0 * 512) : (Mout + (size_t)(m0 - 1536) * 512);
  const int lr = t >> 3;
  const int lc = (t & 7) << 3;
  const int tx = t & 15, ty = t >> 4;

  float4 ra0, ra1, rb0, rb1;
  ra0 = *(const float4*)&Acol[(size_t)lr * lda + lc];
  ra1 = *(const float4*)&Acol[(size_t)lr * lda + lc + 4];
  rb0 = *(const float4*)&Wk[(size_t)lr * 512 + n0 + lc];
  rb1 = *(const float4*)&Wk[(size_t)lr * 512 + n0 + lc + 4];
  float acc[8][4] = {};
  for (int k0 = 0; k0 < 512; k0 += 16) {
    __syncthreads();
    *(float4*)&As[lr][lc] = ra0;
    *(float4*)&As[lr][lc + 4] = ra1;
    *(float4*)&Bs[lr][lc] = rb0;
    *(float4*)&Bs[lr][lc + 4] = rb1;
    __syncthreads();
    if (k0 + 16 < 512) {
      const int kn = k0 + 16 + lr;
      ra0 = *(const float4*)&Acol[(size_t)kn * lda + lc];
      ra1 = *(const float4*)&Acol[(size_t)kn * lda + lc + 4];
      rb0 = *(const float4*)&Wk[(size_t)kn * 512 + n0 + lc];
      rb1 = *(const float4*)&Wk[(size_t)kn * 512 + n0 + lc + 4];
    }
#pragma unroll
    for (int k = 0; k < 16; ++k) {
      float4 a0 = *(float4*)&As[k][ty << 3];
      float4 a1 = *(float4*)&As[k][(ty << 3) + 4];
      float4 b  = *(float4*)&Bs[k][tx << 2];
      float av[8] = {a0.x, a0.y, a0.z, a0.w, a1.x, a1.y, a1.z, a1.w};
      float bv[4] = {b.x, b.y, b.z, b.w};
#pragma unroll
      for (int i = 0; i < 8; ++i)
#pragma unroll
        for (int j = 0; j < 4; ++j) acc[i][j] = fmaf(av[i], bv[j], acc[i][j]);
    }
  }
#pragma unroll
  for (int i = 0; i < 8; ++i) {
    float4 o = {acc[i][0], acc[i][1], acc[i][2], acc[i][3]};
    *(float4*)&Cout[(size_t)((ty << 3) + i) * 512 + n0 + (tx << 2)] = o;
  }
}

// ============================================================================
// gemm_nn2p: 128x64 tile, 8x4 micro, reg-prefetch, split-K to PARTIAL buffers
// (only used for qk = context @ A now)
// ============================================================================
#define AS_STR 132

__global__ __launch_bounds__(256) void gemm_nn2p(const float* __restrict__ A0,
                                                 const float* __restrict__ A1,
                                                 const float* __restrict__ A2,
                                                 const float* __restrict__ B,
                                                 float* __restrict__ Cp,
                                                 int kchunk) {
  __shared__ float As[16 * AS_STR];
  __shared__ float Bs[16 * 64];
  const int t = threadIdx.x;
  const int m0 = blockIdx.x * 128, n0 = blockIdx.y * 64;
  const int kbeg = blockIdx.z * kchunk, kend = kbeg + kchunk;
  float* C = Cp + (size_t)blockIdx.z * (NB * DH);
  const int tx = t & 15, ty = t >> 4;
  const int ar0 = t >> 2;
  const int ak4 = (t & 3) << 2;
  const int bk = t >> 4, bn4 = (t & 15) << 2;

  float4 ra0, ra1, rb;
  {
    const float* base = (kbeg < 512) ? A0 : ((kbeg < 1024) ? A1 : A2);
    const int kk = kbeg & 511;
    ra0 = *(const float4*)&base[(size_t)(m0 + ar0) * 512 + kk + ak4];
    ra1 = *(const float4*)&base[(size_t)(m0 + ar0 + 64) * 512 + kk + ak4];
    rb  = *(const float4*)&B[(size_t)(kbeg + bk) * 512 + n0 + bn4];
  }
  float acc[8][4] = {};
  for (int k0 = kbeg; k0 < kend; k0 += 16) {
    __syncthreads();
    As[(ak4 + 0) * AS_STR + ar0] = ra0.x;
    As[(ak4 + 1) * AS_STR + ar0] = ra0.y;
    As[(ak4 + 2) * AS_STR + ar0] = ra0.z;
    As[(ak4 + 3) * AS_STR + ar0] = ra0.w;
    As[(ak4 + 0) * AS_STR + ar0 + 64] = ra1.x;
    As[(ak4 + 1) * AS_STR + ar0 + 64] = ra1.y;
    As[(ak4 + 2) * AS_STR + ar0 + 64] = ra1.z;
    As[(ak4 + 3) * AS_STR + ar0 + 64] = ra1.w;
    *(float4*)&Bs[bk * 64 + bn4] = rb;
    __syncthreads();
    if (k0 + 16 < kend) {
      const int kn = k0 + 16;
      const float* base = (kn < 512) ? A0 : ((kn < 1024) ? A1 : A2);
      const int kk = kn & 511;
      ra0 = *(const float4*)&base[(size_t)(m0 + ar0) * 512 + kk + ak4];
      ra1 = *(const float4*)&base[(size_t)(m0 + ar0 + 64) * 512 + kk + ak4];
      rb  = *(const float4*)&B[(size_t)(kn + bk) * 512 + n0 + bn4];
    }
#pragma unroll
    for (int k = 0; k < 16; ++k) {
      float4 a0 = *(float4*)&As[k * AS_STR + (ty << 3)];
      float4 a1 = *(float4*)&As[k * AS_STR + (ty << 3) + 4];
      float4 b  = *(float4*)&Bs[k * 64 + (tx << 2)];
      float av[8] = {a0.x, a0.y, a0.z, a0.w, a1.x, a1.y, a1.z, a1.w};
      float bv[4] = {b.x, b.y, b.z, b.w};
#pragma unroll
      for (int i = 0; i < 8; ++i)
#pragma unroll
        for (int j = 0; j < 4; ++j) acc[i][j] = fmaf(av[i], bv[j], acc[i][j]);
    }
  }
#pragma unroll
  for (int i = 0; i < 8; ++i) {
    float4 o = {acc[i][0], acc[i][1], acc[i][2], acc[i][3]};
    *(float4*)&C[(size_t)(m0 + (ty << 3) + i) * 512 + n0 + (tx << 2)] = o;
  }
}

// ============================================================================
// fused_kernel: replaces pass1 + gemm2 + pass2. Two batch-rows per block.
//   A: stream rows b0,b1 from HBM, online exp-accumulate -> Gw[2][512] (LDS)
//   B: gk = Gw @ M with M (1 MB, L2-resident) read ONCE per block for 2 rows
//   C: re-read own rows (b1 first — freshest in L2/L3), u-logits, masked softmax
// The A->C gap contains only phase B (near-zero L3 turnover), so phase C hits
// cache instead of re-streaming 268 MB from HBM.
// ============================================================================
__global__ __launch_bounds__(256, 4) void fused_kernel(const float* __restrict__ HtC,
                                                       const int* __restrict__ caps,
                                                       const int* __restrict__ dists,
                                                       const float* __restrict__ Qkp,
                                                       const float* __restrict__ Mm,
                                                       const float* __restrict__ cap_emb,
                                                       const float* __restrict__ dist_emb,
                                                       const int* __restrict__ need,
                                                       float* __restrict__ out) {
  const int t = threadIdx.x;
  const int wv = t >> 6, ln = t & 63;
  const int b0 = blockIdx.x << 1;

  __shared__ float qk[2][DH];
  __shared__ float Gws[2][DH];
  __shared__ float gks[2][DH];
  __shared__ float gkp[2][2][DH];
  __shared__ float accs[4][DH];
  __shared__ float ec[CC];          // reused as ulog in phase C
  __shared__ float capQ[2][11], distQ[2][3];
  __shared__ float capE[11], distE[3];
  __shared__ float capG[2][11], distG[2][3];
  __shared__ float lsum_s;

  // ---- qk for both rows: sum of 4 split-K partials ----
#pragma unroll
  for (int h = 0; h < 2; ++h) {
    const size_t bo = (size_t)(b0 + h) * DH;
    float q0 = 0.f, q1 = 0.f;
#pragma unroll
    for (int z = 0; z < 4; ++z) {
      q0 += Qkp[(size_t)z * NB * DH + bo + t];
      q1 += Qkp[(size_t)z * NB * DH + bo + 256 + t];
    }
    qk[h][t] = q0;
    qk[h][t + 256] = q1;
  }
  __syncthreads();

  // ---- capQ/distQ (embedding . qk) for both rows ----
#pragma unroll
  for (int h = 0; h < 2; ++h) {
#pragma unroll
    for (int r = 0; r < 3; ++r) {
      int v = wv + (r << 2);
      if (v < 11) {
        float s = 0.f;
#pragma unroll
        for (int j = 0; j < 8; ++j) s = fmaf(cap_emb[v * DH + ln + (j << 6)], qk[h][ln + (j << 6)], s);
        s = wsum(s);
        if (ln == 0) capQ[h][v] = s;
      }
    }
    if (wv < 3) {
      float s = 0.f;
#pragma unroll
      for (int j = 0; j < 8; ++j) s = fmaf(dist_emb[wv * DH + ln + (j << 6)], qk[h][ln + (j << 6)], s);
      s = wsum(s);
      if (ln == 0) distQ[h][wv] = s;
    }
  }

  // ---- phase A: glimpse attention over each row ----
  for (int h = 0; h < 2; ++h) {
    const int b = b0 + h;
    if (t < 11) capE[t] = 0.f;
    if (t < 3) distE[t] = 0.f;
    __syncthreads();   // also covers capQ/distQ writes on h==0
    const float4* qk4 = (const float4*)qk[h];
    float4 q1 = qk4[ln];
    float4 q2 = qk4[64 + ln];
    const float* hb = HtC + (size_t)b * CC * DH;
    float a0 = 0.f, a1 = 0.f, a2 = 0.f, a3 = 0.f, a4 = 0.f, a5 = 0.f, a6 = 0.f, a7 = 0.f;
#pragma unroll 4
    for (int i = 0; i < 16; ++i) {
      int c = (wv << 4) + i;
      const float4* h4 = (const float4*)(hb + (size_t)c * DH);
      float4 h1 = h4[ln];
      float4 h2 = h4[64 + ln];
      float s = h1.x * q1.x + h1.y * q1.y + h1.z * q1.z + h1.w * q1.w +
                h2.x * q2.x + h2.y * q2.y + h2.z * q2.z + h2.w * q2.w;
      s = wsum(s);
      float logit = SCALE * (s + capQ[h][caps[b * CC + c]] + distQ[h][dists[b * CC + c]]);
      float e = __expf(logit);
      if (ln == 0) ec[c] = e;
      a0 = fmaf(e, h1.x, a0); a1 = fmaf(e, h1.y, a1);
      a2 = fmaf(e, h1.z, a2); a3 = fmaf(e, h1.w, a3);
      a4 = fmaf(e, h2.x, a4); a5 = fmaf(e, h2.y, a5);
      a6 = fmaf(e, h2.z, a6); a7 = fmaf(e, h2.w, a7);
    }
    {
      int d0 = ln << 2;
      accs[wv][d0 + 0] = a0; accs[wv][d0 + 1] = a1;
      accs[wv][d0 + 2] = a2; accs[wv][d0 + 3] = a3;
      accs[wv][256 + d0 + 0] = a4; accs[wv][256 + d0 + 1] = a5;
      accs[wv][256 + d0 + 2] = a6; accs[wv][256 + d0 + 3] = a7;
    }
    __syncthreads();
    if (t < CC) {
      float e = ec[t];
      float l = wsum(e);
      if (t == 0) lsum_s = l;
      atomicAdd(&capE[caps[b * CC + t]], e);
      atomicAdd(&distE[dists[b * CC + t]], e);
    }
    __syncthreads();
    const float rinv = 1.0f / lsum_s;
#pragma unroll
    for (int dd = 0; dd < 2; ++dd) {
      int d = t + (dd << 8);
      float g = accs[0][d] + accs[1][d] + accs[2][d] + accs[3][d];
#pragma unroll
      for (int v = 0; v < 11; ++v) g = fmaf(capE[v], cap_emb[v * DH + d], g);
#pragma unroll
      for (int v = 0; v < 3; ++v) g = fmaf(distE[v], dist_emb[v * DH + d], g);
      Gws[h][d] = g * rinv;
    }
    __syncthreads();
  }

  // ---- phase B: gk[h] = Gw[h] @ M, M streamed once (coalesced float4) ----
  {
    const int e4 = (t & 127) << 2;   // 128 threads cover e in [0,512) as float4
    const int half = t >> 7;         // d-range split: [0,256) / [256,512)
    const float* Mp = Mm + (size_t)(half << 8) * DH + e4;
    const float* g0p = &Gws[0][half << 8];
    const float* g1p = &Gws[1][half << 8];
    float s00 = 0.f, s01 = 0.f, s02 = 0.f, s03 = 0.f;
    float s10 = 0.f, s11 = 0.f, s12 = 0.f, s13 = 0.f;
#pragma unroll 8
    for (int d = 0; d < 256; ++d) {
      float4 m4 = *(const float4*)&Mp[(size_t)d * DH];
      float g0 = g0p[d];
      float g1 = g1p[d];
      s00 = fmaf(g0, m4.x, s00); s01 = fmaf(g0, m4.y, s01);
      s02 = fmaf(g0, m4.z, s02); s03 = fmaf(g0, m4.w, s03);
      s10 = fmaf(g1, m4.x, s10); s11 = fmaf(g1, m4.y, s11);
      s12 = fmaf(g1, m4.z, s12); s13 = fmaf(g1, m4.w, s13);
    }
    gkp[half][0][e4 + 0] = s00; gkp[half][0][e4 + 1] = s01;
    gkp[half][0][e4 + 2] = s02; gkp[half][0][e4 + 3] = s03;
    gkp[half][1][e4 + 0] = s10; gkp[half][1][e4 + 1] = s11;
    gkp[half][1][e4 + 2] = s12; gkp[half][1][e4 + 3] = s13;
  }
  __syncthreads();
#pragma unroll
  for (int h = 0; h < 2; ++h) {
    gks[h][t] = gkp[0][h][t] + gkp[1][h][t];
    gks[h][t + 256] = gkp[0][h][t + 256] + gkp[1][h][t + 256];
  }
  __syncthreads();

  // ---- capG/distG (embedding . gk) for both rows ----
#pragma unroll
  for (int h = 0; h < 2; ++h) {
#pragma unroll
    for (int r = 0; r < 3; ++r) {
      int v = wv + (r << 2);
      if (v < 11) {
        float s = 0.f;
#pragma unroll
        for (int j = 0; j < 8; ++j) s = fmaf(cap_emb[v * DH + ln + (j << 6)], gks[h][ln + (j << 6)], s);
        s = wsum(s);
        if (ln == 0) capG[h][v] = s;
      }
    }
    if (wv < 3) {
      float s = 0.f;
#pragma unroll
      for (int j = 0; j < 8; ++j) s = fmaf(dist_emb[wv * DH + ln + (j << 6)], gks[h][ln + (j << 6)], s);
      s = wsum(s);
      if (ln == 0) distG[h][wv] = s;
    }
  }
  __syncthreads();

  // ---- phase C: pointer logits + capacity-masked softmax (b1 first) ----
  for (int h = 1; h >= 0; --h) {
    const int b = b0 + h;
    const float4* gk4 = (const float4*)gks[h];
    float4 q1 = gk4[ln];
    float4 q2 = gk4[64 + ln];
    const float* hb = HtC + (size_t)b * CC * DH;
#pragma unroll 4
    for (int i = 0; i < 16; ++i) {
      int c = (wv << 4) + i;
      const float4* h4 = (const float4*)(hb + (size_t)c * DH);
      float4 h1 = h4[ln];
      float4 h2 = h4[64 + ln];
      float s = h1.x * q1.x + h1.y * q1.y + h1.z * q1.z + h1.w * q1.w +
                h2.x * q2.x + h2.y * q2.y + h2.z * q2.z + h2.w * q2.w;
      s = wsum(s);
      if (ln == 0)
        ec[c] = SCALE * (s + capG[h][caps[b * CC + c]] + distG[h][dists[b * CC + c]]);
    }
    __syncthreads();
    if (t < CC) {
      int nb = need[b];
      float x = ec[t];
      if (caps[b * CC + t] < nb) x = -INFINITY;
      float m = x;
#pragma unroll
      for (int off = 32; off; off >>= 1) m = fmaxf(m, __shfl_xor(m, off, 64));
      float e = __expf(x - m);
      float ssum = wsum(e);
      out[(size_t)b * CC + t] = e / ssum;
    }
    __syncthreads();
  }
}

// ---------------- launch ----------------
extern "C" void kernel_launch(void* const* d_in, const int* in_sizes, int n_in,
                              void* d_out, int out_size, void* d_ws, size_t ws_size,
                              hipStream_t stream) {
  const float* HtC      = (const float*)d_in[0];
  const int* caps       = (const int*)d_in[1];
  const int* dists      = (const int*)d_in[2];
  const float* H_X      = (const float*)d_in[3];
  const float* Ht_S     = (const float*)d_in[4];
  const float* Eq_Q     = (const float*)d_in[5];
  const unsigned char* dbl = (const unsigned char*)d_in[6];
  const float* cap_emb  = (const float*)d_in[7];
  const float* dist_emb = (const float*)d_in[8];
  const float* W_q      = (const float*)d_in[9];
  const float* W_k      = (const float*)d_in[10];
  const float* W_v      = (const float*)d_in[11];
  float* out = (float*)d_out;

  float* ws     = (float*)d_ws;
  float* wsA    = ws;                        // [1536,512]     A = W_q^T @ W_k
  float* wsM    = wsA + 1536 * 512;          // [512,512]      M = W_v^T @ W_k
  float* wsQkp  = wsM + 512 * 512;           // [4][2048,512]  Qk split-K partials
  int* wsNeed   = (int*)(wsQkp + 4 * 2048 * 512);

  pre_kernel<<<257, 128, 0, stream>>>(W_q, W_v, W_k, wsA, wsM, dbl, wsNeed);
  gemm_nn2p<<<dim3(16, 8, 4), 256, 0, stream>>>(H_X, Ht_S, Eq_Q, wsA, wsQkp, 384);
  fused_kernel<<<NB / 2, 256, 0, stream>>>(HtC, caps, dists, wsQkp, wsM,
                                           cap_emb, dist_emb, wsNeed, out);
}